// Round 1
// 594.025 us; speedup vs baseline: 1.0018x; 1.0018x over previous
//
#include <hip/hip_runtime.h>
#include <cstdint>

// Problem constants (fixed by reference)
#define C_   1024
#define IN_  256
#define OUT_ 256
#define B_   256
#define N_   1024

#define NTHREADS 512
#define WLD 260   // padded row stride (floats) for W transpose staging

typedef __attribute__((ext_vector_type(8))) short short8;   // 8 bf16 (4 VGPRs)
typedef __attribute__((ext_vector_type(4))) float f32x4;    // MFMA accumulator

// fp32 -> bf16, round-to-nearest-even
__device__ __forceinline__ uint16_t f2bf(float f) {
    uint32_t u = __builtin_bit_cast(uint32_t, f);
    return (uint16_t)((u + 0x7FFFu + ((u >> 16) & 1u)) >> 16);
}

// ---------------------------------------------------------------------------
// Fused kernel: one block per batch. W[idx[b]] (fp32 [IN][OUT]) is loaded
// once, transposed through LDS, converted to bf16 and kept in REGISTERS as
// MFMA B-fragments (64 VGPR/lane). Main loop streams x through a
// double-buffered LDS tile (1 barrier per K-step, 2-step global prefetch).
// Epilogue stores directly to global (64B runs per 16-lane group; L2
// write-combines full lines since the block covers every byte).
//
// 8 waves: wave wv owns output cols [wv*32, wv*32+32) x all 128 rows of the
// n-tile -> acc[8 mi][2 ni] f32x4, bb[8 kt][2 ni] short8.
// grid (B_), 512 threads.
// ---------------------------------------------------------------------------
__global__ __launch_bounds__(NTHREADS, 2) void fused_gemm(
    const float* __restrict__ x, const int* __restrict__ idx,
    const float* __restrict__ weight, const float* __restrict__ bias,
    float* __restrict__ out) {
    __shared__ __align__(16) uint8_t smem[WLD * 32 * 4];   // 33280 B
    float*    wstg = (float*)smem;                 // [32][WLD] fp32 (init)
    uint16_t* As0  = (uint16_t*)smem;              // [128][32] bf16 (main)
    uint16_t* As1  = (uint16_t*)(smem + 8192);

    const int b    = blockIdx.x;
    const int t    = threadIdx.x;
    const int lane = t & 63;
    const int wv   = t >> 6;            // wave id 0..7 -> col slice
    const int m    = lane & 15;
    const int g    = lane >> 4;
    const int ci   = idx[b];

    const float* xsrc = x      + (size_t)b  * (N_ * IN_);
    const float* wsrc = weight + (size_t)ci * (IN_ * OUT_);
    float*       odst = out    + (size_t)b  * (N_ * OUT_);

    // ---- x prefetch for steps 0,1 (issued before W init so HBM stays busy)
    const int arow = t >> 2, aq = t & 3;         // row 0..127, 8-float quarter
    const float* abase = xsrc + arow * IN_ + aq * 8;
    float4 xe0 = *(const float4*)(abase);
    float4 xe1 = *(const float4*)(abase + 4);
    float4 xo0 = *(const float4*)(abase + 32);
    float4 xo1 = *(const float4*)(abase + 36);

    // ---- W: load fp32 coalesced -> LDS transpose tile -> bf16 frags in regs
    short8 bb[8][2];
    const int wrow = t >> 6;            // 0..7: one row per wave per round
    const int wc   = (t & 63) * 4;      // float4 col
    const float* wbase = wsrc + wrow * OUT_ + wc;
    float4 wA[4], wB[4];
    #pragma unroll
    for (int r = 0; r < 4; ++r)
        wA[r] = *(const float4*)(wbase + (r * 8) * OUT_);
    #pragma unroll
    for (int kc = 0; kc < 8; ++kc) {
        float4* wr = (kc & 1) ? wB : wA;
        #pragma unroll
        for (int r = 0; r < 4; ++r)
            *(float4*)(wstg + (r * 8 + wrow) * WLD + wc) = wr[r];
        __syncthreads();
        if (kc < 7) {   // prefetch next chunk while this one is consumed
            float4* wnx = (kc & 1) ? wA : wB;
            #pragma unroll
            for (int r = 0; r < 4; ++r)
                wnx[r] = *(const float4*)(wbase + ((kc + 1) * 32 + r * 8) * OUT_);
        }
        #pragma unroll
        for (int ni = 0; ni < 2; ++ni) {
            const int o = wv * 32 + ni * 16 + m;
            short8 f;
            #pragma unroll
            for (int j = 0; j < 8; ++j)
                f[j] = (short)f2bf(wstg[(g * 8 + j) * WLD + o]);
            bb[kc][ni] = f;
        }
        __syncthreads();   // before wstg reuse (next chunk / As)
    }

    float bv[2];
    #pragma unroll
    for (int ni = 0; ni < 2; ++ni)
        bv[ni] = bias[(size_t)ci * OUT_ + wv * 32 + ni * 16 + m];

    // ---- main loop: 8 n-tiles x 8 K-steps, W entirely in registers
    f32x4 acc[8][2] = {};
    for (int nt = 0; nt < 8; ++nt) {
        #pragma unroll
        for (int kt = 0; kt < 8; ++kt) {
            uint16_t* Asb = (kt & 1) ? As1 : As0;
            float4 c0 = (kt & 1) ? xo0 : xe0;
            float4 c1 = (kt & 1) ? xo1 : xe1;
            // stage x: 8 fp32 -> 8 bf16, one b128 LDS write
            {
                float af[8] = {c0.x, c0.y, c0.z, c0.w,
                               c1.x, c1.y, c1.z, c1.w};
                union { uint16_t u[8]; uint4 v; } pk;
                #pragma unroll
                for (int i = 0; i < 8; ++i) pk.u[i] = f2bf(af[i]);
                *(uint4*)&Asb[arow * 32 + aq * 8] = pk.v;
            }
            // prefetch step s+2 into the reg pair just consumed
            {
                const int s2 = nt * 8 + kt + 2;
                if (s2 < 64) {
                    const float* p = xsrc + ((s2 >> 3) * 128 + arow) * IN_
                                     + (s2 & 7) * 32 + aq * 8;
                    float4 n0 = *(const float4*)(p);
                    float4 n1 = *(const float4*)(p + 4);
                    if (kt & 1) { xo0 = n0; xo1 = n1; }
                    else        { xe0 = n0; xe1 = n1; }
                }
            }
            __syncthreads();   // As writes visible; also fences prior reads
            short8 a[8];
            #pragma unroll
            for (int mi = 0; mi < 8; ++mi)
                a[mi] = *(const short8*)&Asb[(mi * 16 + m) * 32 + g * 8];
            #pragma unroll
            for (int mi = 0; mi < 8; ++mi)
                #pragma unroll
                for (int ni = 0; ni < 2; ++ni)
                    acc[mi][ni] = __builtin_amdgcn_mfma_f32_16x16x32_bf16(
                        a[mi], bb[kt][ni], acc[mi][ni], 0, 0, 0);
        }
        // epilogue: direct stores. per (mi,ni,v): 16 lanes write 64B runs on
        // 4 rows; block covers all 256 cols of each row -> L2 write-combines.
        float* obase = odst + (size_t)(nt * 128) * OUT_;
        #pragma unroll
        for (int mi = 0; mi < 8; ++mi)
            #pragma unroll
            for (int ni = 0; ni < 2; ++ni) {
                #pragma unroll
                for (int v = 0; v < 4; ++v)
                    obase[(mi * 16 + g * 4 + v) * OUT_ + wv * 32 + ni * 16 + m]
                        = acc[mi][ni][v] + bv[ni];
                acc[mi][ni] = (f32x4){0.f, 0.f, 0.f, 0.f};
            }
    }
}

// ---------------------------------------------------------------------------
extern "C" void kernel_launch(void* const* d_in, const int* in_sizes, int n_in,
                              void* d_out, int out_size, void* d_ws, size_t ws_size,
                              hipStream_t stream) {
    const float* x      = (const float*)d_in[0];
    const int*   idx    = (const int*)d_in[1];
    const float* weight = (const float*)d_in[2];
    const float* bias   = (const float*)d_in[3];
    float*       out    = (float*)d_out;
    (void)d_ws; (void)ws_size;

    fused_gemm<<<dim3(B_), NTHREADS, 0, stream>>>(x, idx, weight, bias, out);
}